// Round 20
// baseline (266.312 us; speedup 1.0000x reference)
//
#include <hip/hip_runtime.h>
#include <hip/hip_bf16.h>
#include <math.h>

#define N_NODES 8192
#define IN_DIM  512
#define H_DIM   128
#define KC      1024              // K-chunk per k_A block
#define NKB     (N_NODES / KC)    // 8
#define NTW     (N_NODES / 64)    // bitmask u64 words per row (128)
#define NB_WH   (N_NODES / 32)    // 256 wh tiles
#define NB_ROW  (N_NODES / 4)     // 2048 row-stream blocks (4 rows/block)
#define NB_A2   ((N_NODES / 128) * NKB)    // 512 k_A blocks (dual-frag, 32 rows/wave)

typedef __attribute__((ext_vector_type(8))) short bf16x8;
typedef __attribute__((ext_vector_type(4))) float f32x4;

__device__ __forceinline__ float lrelu(float x) { return fmaxf(x, 0.2f * x); }

__device__ __forceinline__ unsigned int f2mono(float x) {
    unsigned int b = __float_as_uint(x);
    return (b & 0x80000000u) ? ~b : (b | 0x80000000u);
}
__device__ __forceinline__ float mono2f(unsigned int u) {
    unsigned int b = (u & 0x80000000u) ? (u ^ 0x80000000u) : ~u;
    return __uint_as_float(b);
}

__device__ __forceinline__ short f2bf(float x) {
    union { __hip_bfloat16 h; short s; } cv;
    cv.h = __float2bfloat16(x);
    return cv.s;
}

// w_a = W_w^T @ a (512), b_a = W_b . a, smax init. One block.
__global__ __launch_bounds__(256) void k_wa(const float* __restrict__ Ww,
                                            const float* __restrict__ Wb,
                                            const float* __restrict__ a,
                                            float* __restrict__ wa,
                                            float* __restrict__ ba,
                                            unsigned int* __restrict__ smax) {
    const int t = threadIdx.x;
    #pragma unroll
    for (int kk = 0; kk < 2; ++kk) {
        int k = t + kk * 256;
        float sum = 0.f;
        #pragma unroll 8
        for (int c = 0; c < H_DIM; ++c)
            sum += Ww[(size_t)c * IN_DIM + k] * a[c];
        wa[k] = sum;
    }
    __shared__ float red[256];
    red[t] = (t < H_DIM) ? Wb[t] * a[t] : 0.f;
    __syncthreads();
    for (int off = 128; off > 0; off >>= 1) {
        if (t < off) red[t] += red[t + off];
        __syncthreads();
    }
    if (t == 0) { ba[0] = red[0]; *smax = 0u; }
}

// s_i = h_i . w_a + b_a ; smax via mapped atomicMax. 4 rows/block (wave each).
__global__ __launch_bounds__(256) void k_s0(const float* __restrict__ h,
                                            const float* __restrict__ wa,
                                            const float* __restrict__ ba,
                                            float* __restrict__ s,
                                            unsigned int* __restrict__ smax) {
    const int w = threadIdx.x >> 6, lane = threadIdx.x & 63;
    const int row = blockIdx.x * 4 + w;
    const float* hp = h + (size_t)row * IN_DIM + lane * 8;
    f32x4 h0 = *(const f32x4*)(hp);
    f32x4 h1 = *(const f32x4*)(hp + 4);
    f32x4 w0 = *(const f32x4*)(wa + lane * 8);
    f32x4 w1 = *(const f32x4*)(wa + lane * 8 + 4);
    float v = h0[0]*w0[0] + h0[1]*w0[1] + h0[2]*w0[2] + h0[3]*w0[3]
            + h1[0]*w1[0] + h1[1]*w1[1] + h1[2]*w1[2] + h1[3]*w1[3];
    #pragma unroll
    for (int off = 32; off > 0; off >>= 1) v += __shfl_down(v, off);
    __shared__ float bmax[4];
    if (lane == 0) { float sv = v + ba[0]; s[row] = sv; bmax[w] = sv; }
    __syncthreads();
    if (threadIdx.x == 0) {
        float m = fmaxf(fmaxf(bmax[0], bmax[1]), fmaxf(bmax[2], bmax[3]));
        atomicMax(smax, f2mono(m));
    }
}

// ---------------- fused rowfront: k_wh || (mask + denom + ALPHA) -------------
// r19 post-mortem: A/B overlap is worth ~0 in every config (both sides are
// memory-system-bound; times add). So remove the separate alpha phase instead:
// each row wave keeps its 128 mask bits in 4 u32 REGISTERS during the adj
// stream (sweep 1: bits -> regs + global bitmask for k_A, exp-sum -> denom),
// butterfly-broadcasts denom, then sweep 2 recomputes ex from register bits +
// L1-resident s and writes the alpha row immediately. k_B disappears: alpha
// rides the same kernel as the adj read; chain is rowfront -> k_A -> z2.
__global__ __launch_bounds__(256) void k_rowfront(const float* __restrict__ h,
                                                  const float* __restrict__ Ww,
                                                  const float* __restrict__ Wb,
                                                  __hip_bfloat16* __restrict__ WhT2,
                                                  const float* __restrict__ adj,
                                                  unsigned long long* __restrict__ bm,
                                                  const float* __restrict__ s,
                                                  const unsigned int* __restrict__ smaxp,
                                                  float* __restrict__ denom,
                                                  float* __restrict__ alpha) {
    __shared__ float hT[64][32 + 4];
    __shared__ float wT[64][H_DIM + 4];
    const int tid = threadIdx.x;
    const int bx = blockIdx.x;

    if (bx < NB_WH) {
        // ---- Wh GEMM -> WhT2 fragment-swizzled bf16 ----
        const int w = tid >> 6, lane = tid & 63;
        const int trm = tid >> 5, tcm = tid & 31;
        const int row0 = bx * 32;

        float acc[4][4] = {};
        for (int k0 = 0; k0 < IN_DIM; k0 += 64) {
            __syncthreads();
            #pragma unroll
            for (int p = 0; p < 8; ++p) {
                int r = 4 * p + w;
                hT[lane][r] = h[(size_t)(row0 + r) * IN_DIM + k0 + lane];
            }
            #pragma unroll
            for (int p = 0; p < 32; ++p) {
                int c = 4 * p + w;
                wT[lane][c] = Ww[(size_t)c * IN_DIM + k0 + lane];
            }
            __syncthreads();
            #pragma unroll 8
            for (int kk = 0; kk < 64; ++kk) {
                f32x4 a4 = *(const f32x4*)&hT[kk][4 * trm];
                f32x4 b4 = *(const f32x4*)&wT[kk][4 * tcm];
                #pragma unroll
                for (int i = 0; i < 4; ++i)
                    #pragma unroll
                    for (int j = 0; j < 4; ++j)
                        acc[i][j] = fmaf(a4[i], b4[j], acc[i][j]);
            }
        }
        f32x4 wb4 = *(const f32x4*)&Wb[4 * tcm];
        #pragma unroll
        for (int i = 0; i < 4; ++i) {
            int row = row0 + 4 * trm + i;          // node j
            int ts = row >> 5, kq = (row >> 3) & 3, e = row & 7;
            #pragma unroll
            for (int jj = 0; jj < 4; ++jj) {
                int c = 4 * tcm + jj;
                int f = c >> 4, r16 = c & 15;
                WhT2[((size_t)(ts * 8 + f) * 64 + kq * 16 + r16) * 8 + e] =
                    __float2bfloat16(acc[i][jj] + wb4[jj]);
            }
        }
    } else {
        const int lane = tid & 63;
        const int row = (bx - NB_WH) * 4 + (tid >> 6);
        const float* arow = adj + (size_t)row * N_NODES;
        unsigned long long* mrow = bm + (size_t)row * NTW;
        const float smax = mono2f(*smaxp);
        const float si = s[row];
        const float mi = lrelu(si + smax);
        float dsum = 0.f;
        unsigned int mybits[4] = {0u, 0u, 0u, 0u};   // this lane's 128 mask bits

        // ---- sweep 1: adj stream -> bits (regs + global bitmask), denom ----
        #pragma unroll 4
        for (int c = 0; c < N_NODES / 256; ++c) {    // 32 iters, 1KB/wave each
            int col = c * 256 + lane * 4;
            f32x4 a4 = __builtin_nontemporal_load((const f32x4*)(arow + col));
            f32x4 sj = *(const f32x4*)&s[col];
            unsigned int b4 = 0u;
            #pragma unroll
            for (int q = 0; q < 4; ++q) {
                bool nb = (a4[q] != 0.f);
                b4 |= nb ? (1u << q) : 0u;
                dsum += nb ? __expf(lrelu(si + sj[q]) - mi) : 0.f;
            }
            mybits[c >> 3] |= b4 << ((c & 7) * 4);
            // global bitmask word for k_A (cross-lane pack within 16-lane group)
            unsigned long long v = (unsigned long long)b4 << (4 * (lane & 15));
            v |= __shfl_xor(v, 1);
            v |= __shfl_xor(v, 2);
            v |= __shfl_xor(v, 4);
            v |= __shfl_xor(v, 8);
            if ((lane & 15) == 0)
                mrow[c * 4 + (lane >> 4)] = v;
        }
        // full 64-lane butterfly: every lane gets the row total
        #pragma unroll
        for (int off = 1; off < 64; off <<= 1) dsum += __shfl_xor(dsum, off);
        if (lane == 0) denom[row] = dsum;
        const float rd = dsum > 0.f ? 1.f / dsum : 0.f;

        // ---- sweep 2: alpha row from register bits (s is L1-resident) ----
        float* arw = alpha + (size_t)row * N_NODES;
        #pragma unroll 4
        for (int c = 0; c < N_NODES / 256; ++c) {
            int col = c * 256 + lane * 4;
            unsigned int b4 = (mybits[c >> 3] >> ((c & 7) * 4)) & 0xfu;
            f32x4 sj = *(const f32x4*)&s[col];
            f32x4 o;
            o[0] = (b4 & 1u) ? __expf(lrelu(si + sj[0]) - mi) * rd : 0.f;
            o[1] = (b4 & 2u) ? __expf(lrelu(si + sj[1]) - mi) * rd : 0.f;
            o[2] = (b4 & 4u) ? __expf(lrelu(si + sj[2]) - mi) * rd : 0.f;
            o[3] = (b4 & 8u) ? __expf(lrelu(si + sj[3]) - mi) * rd : 0.f;
            __builtin_nontemporal_store(o, (f32x4*)&arw[col]);
        }
    }
}

// ---------------- k_A standalone: dual-frag MFMA (r16's proven config) -------
// Each wave owns 32 rows (two A-fragments) x all 128 H cols; 8 bc loads feed
// 16 MFMAs per substep. ypart plain stores; grid 512 blocks (64 row-blocks x
// 8 k-chunks).
__global__ __launch_bounds__(256) void k_A(const unsigned long long* __restrict__ bm,
                                           const __hip_bfloat16* __restrict__ WhT2,
                                           const float* __restrict__ s,
                                           const unsigned int* __restrict__ smaxp,
                                           float* __restrict__ ypart) {
    const int lane = threadIdx.x & 63;
    const int w    = threadIdx.x >> 6;
    const int r16  = lane & 15;
    const int kq   = lane >> 4;
    const int xb   = blockIdx.x & 63;
    const int yb   = blockIdx.x >> 6;
    const int rowB = xb * 128 + w * 32;
    const int j0   = yb * KC;
    const int rowA0 = rowB + r16;
    const int rowA1 = rowB + 16 + r16;

    const float smax = mono2f(*smaxp);
    const float si0 = s[rowA0], si1 = s[rowA1];
    const float mi0 = lrelu(si0 + smax), mi1 = lrelu(si1 + smax);

    f32x4 acc0[8], acc1[8];
    {
        f32x4 zv = {0.f, 0.f, 0.f, 0.f};
        #pragma unroll
        for (int f = 0; f < 8; ++f) { acc0[f] = zv; acc1[f] = zv; }
    }
    const float* sp = s + j0 + kq * 8;
    const unsigned long long* mrow0 = bm + (size_t)rowA0 * NTW + (j0 >> 6);
    const unsigned long long* mrow1 = bm + (size_t)rowA1 * NTW + (j0 >> 6);

    for (int bs = 0; bs < KC / 64; ++bs) {
        unsigned long long m64a = mrow0[bs];
        unsigned long long m64b = mrow1[bs];
        #pragma unroll
        for (int sub = 0; sub < 2; ++sub) {
            const int ts = bs * 2 + sub;
            unsigned int bits0 = (unsigned int)(m64a >> (sub * 32 + kq * 8)) & 0xffu;
            unsigned int bits1 = (unsigned int)(m64b >> (sub * 32 + kq * 8)) & 0xffu;

            f32x4 sc0 = *(const f32x4*)(sp + ts * 32);
            f32x4 sc1 = *(const f32x4*)(sp + ts * 32 + 4);
            float sv[8] = {sc0[0], sc0[1], sc0[2], sc0[3], sc1[0], sc1[1], sc1[2], sc1[3]};
            bf16x8 af0, af1;
            #pragma unroll
            for (int e = 0; e < 8; ++e) {
                float ex0 = ((bits0 >> e) & 1u) ? __expf(lrelu(si0 + sv[e]) - mi0) : 0.f;
                float ex1 = ((bits1 >> e) & 1u) ? __expf(lrelu(si1 + sv[e]) - mi1) : 0.f;
                af0[e] = f2bf(ex0);
                af1[e] = f2bf(ex1);
            }
            const __hip_bfloat16* base =
                WhT2 + (size_t)((j0 >> 5) + ts) * 4096 + lane * 8;
            #pragma unroll
            for (int half = 0; half < 2; ++half) {
                bf16x8 bc[4];
                #pragma unroll
                for (int f = 0; f < 4; ++f)
                    bc[f] = *(const bf16x8*)(base + (half * 4 + f) * 512);
                #pragma unroll
                for (int f = 0; f < 4; ++f) {
                    acc0[half * 4 + f] =
                        __builtin_amdgcn_mfma_f32_16x16x32_bf16(af0, bc[f], acc0[half * 4 + f], 0, 0, 0);
                    acc1[half * 4 + f] =
                        __builtin_amdgcn_mfma_f32_16x16x32_bf16(af1, bc[f], acc1[half * 4 + f], 0, 0, 0);
                }
            }
        }
    }
    float* yp = ypart + (size_t)yb * N_NODES * H_DIM;
    #pragma unroll
    for (int f = 0; f < 8; ++f)
        #pragma unroll
        for (int i = 0; i < 4; ++i) {
            int cc = f * 16 + r16;
            yp[(size_t)(rowB + kq * 4 + i) * H_DIM + cc] = acc0[f][i];
            yp[(size_t)(rowB + 16 + kq * 4 + i) * H_DIM + cc] = acc1[f][i];
        }
}

// z = sigmoid(sum_p ypart[p]/denom)
__global__ __launch_bounds__(256) void k_z2(const float* __restrict__ ypart,
                                            const float* __restrict__ denom,
                                            float* __restrict__ z) {
    int i = blockIdx.x * 256 + threadIdx.x;
    int row = i >> 7;
    float d = denom[row];
    float rd = d > 0.f ? 1.f / d : 0.f;
    float v = 0.f;
    #pragma unroll
    for (int p = 0; p < NKB; ++p)
        v += ypart[(size_t)p * N_NODES * H_DIM + i];
    v *= rd;
    z[i] = 1.f / (1.f + __expf(-v));
}

// ---------------- fallback path (ws too small): serial, adj-direct ----------------
__global__ __launch_bounds__(256) void k_zero(f32x4* __restrict__ p, int n16) {
    int i = blockIdx.x * 256 + threadIdx.x;
    if (i < n16) {
        f32x4 zv = {0.f, 0.f, 0.f, 0.f};
        __builtin_nontemporal_store(zv, p + i);
    }
}

__global__ __launch_bounds__(256) void k_wh_fb(const float* __restrict__ h,
                                               const float* __restrict__ Ww,
                                               const float* __restrict__ Wb,
                                               __hip_bfloat16* __restrict__ WhT2) {
    __shared__ float hT[64][32 + 4];
    __shared__ float wT[64][H_DIM + 4];
    const int tid = threadIdx.x;
    const int w = tid >> 6, lane = tid & 63;
    const int trm = tid >> 5, tcm = tid & 31;
    const int row0 = blockIdx.x * 32;

    float acc[4][4] = {};
    for (int k0 = 0; k0 < IN_DIM; k0 += 64) {
        __syncthreads();
        #pragma unroll
        for (int p = 0; p < 8; ++p) {
            int r = 4 * p + w;
            hT[lane][r] = h[(size_t)(row0 + r) * IN_DIM + k0 + lane];
        }
        #pragma unroll
        for (int p = 0; p < 32; ++p) {
            int c = 4 * p + w;
            wT[lane][c] = Ww[(size_t)c * IN_DIM + k0 + lane];
        }
        __syncthreads();
        #pragma unroll 8
        for (int kk = 0; kk < 64; ++kk) {
            f32x4 a4 = *(const f32x4*)&hT[kk][4 * trm];
            f32x4 b4 = *(const f32x4*)&wT[kk][4 * tcm];
            #pragma unroll
            for (int i = 0; i < 4; ++i)
                #pragma unroll
                for (int j = 0; j < 4; ++j)
                    acc[i][j] = fmaf(a4[i], b4[j], acc[i][j]);
        }
    }
    f32x4 wb4 = *(const f32x4*)&Wb[4 * tcm];
    #pragma unroll
    for (int i = 0; i < 4; ++i) {
        int row = row0 + 4 * trm + i;
        int ts = row >> 5, kq = (row >> 3) & 3, e = row & 7;
        #pragma unroll
        for (int jj = 0; jj < 4; ++jj) {
            int c = 4 * tcm + jj;
            int f = c >> 4, r16 = c & 15;
            WhT2[((size_t)(ts * 8 + f) * 64 + kq * 16 + r16) * 8 + e] =
                __float2bfloat16(acc[i][jj] + wb4[jj]);
        }
    }
}

__global__ __launch_bounds__(256) void k_A_fb(const float* __restrict__ adj,
                                              const __hip_bfloat16* __restrict__ WhT2,
                                              const float* __restrict__ s,
                                              const unsigned int* __restrict__ smaxp,
                                              float* __restrict__ denom,
                                              float* __restrict__ y) {
    __shared__ unsigned char msk[64 * 64];
    const int tid  = threadIdx.x;
    const int lane = tid & 63;
    const int w    = tid >> 6;
    const int r16  = lane & 15;
    const int kq   = lane >> 4;
    const int row0 = blockIdx.x * 64;
    const int j0base = blockIdx.y * KC;
    const int rowA = row0 + w * 16 + r16;

    const float smax = mono2f(*smaxp);
    const float si = s[rowA];
    const float mi = lrelu(si + smax);

    f32x4 acc[8];
    {
        f32x4 zv = {0.f, 0.f, 0.f, 0.f};
        #pragma unroll
        for (int f = 0; f < 8; ++f) acc[f] = zv;
    }
    float dsum = 0.f;
    const float* sp = s + j0base + kq * 8;

    int sRow[4], sCol[4];
    #pragma unroll
    for (int p = 0; p < 4; ++p) {
        int seg = p * 256 + tid;
        sRow[p] = seg >> 4;
        sCol[p] = (seg & 15) * 4;
    }
    const int NBIG = KC / 64;
    f32x4 areg[4];
    #pragma unroll
    for (int p = 0; p < 4; ++p)
        areg[p] = __builtin_nontemporal_load(
            (const f32x4*)(adj + (size_t)(row0 + sRow[p]) * N_NODES + j0base + sCol[p]));

    for (int bs = 0; bs < NBIG; ++bs) {
        __syncthreads();
        #pragma unroll
        for (int p = 0; p < 4; ++p) {
            f32x4 a4 = areg[p];
            unsigned int mwd = 0u;
            mwd |= (a4[0] != 0.f) ? 0x00000001u : 0u;
            mwd |= (a4[1] != 0.f) ? 0x00000100u : 0u;
            mwd |= (a4[2] != 0.f) ? 0x00010000u : 0u;
            mwd |= (a4[3] != 0.f) ? 0x01000000u : 0u;
            int r = sRow[p], c = sCol[p];
            int slot = (c >> 3) ^ (r & 7);
            *(unsigned int*)&msk[r * 64 + (slot << 3) + (c & 7)] = mwd;
        }
        __syncthreads();
        if (bs + 1 < NBIG) {
            const int j1 = j0base + (bs + 1) * 64;
            #pragma unroll
            for (int p = 0; p < 4; ++p)
                areg[p] = __builtin_nontemporal_load(
                    (const f32x4*)(adj + (size_t)(row0 + sRow[p]) * N_NODES + j1 + sCol[p]));
        }
        #pragma unroll
        for (int sub = 0; sub < 2; ++sub) {
            const int ts = bs * 2 + sub;
            const int rT = w * 16 + r16;
            const int slotR = (sub * 4 + kq) ^ (r16 & 7);
            unsigned long long m8 = *(const unsigned long long*)&msk[rT * 64 + (slotR << 3)];
            unsigned int bits = (unsigned int)((m8 * 0x0102040810204080ull) >> 56) & 0xffu;

            f32x4 sc0 = *(const f32x4*)(sp + ts * 32);
            f32x4 sc1 = *(const f32x4*)(sp + ts * 32 + 4);
            float sv[8] = {sc0[0], sc0[1], sc0[2], sc0[3], sc1[0], sc1[1], sc1[2], sc1[3]};
            bf16x8 afrag;
            #pragma unroll
            for (int e = 0; e < 8; ++e) {
                bool nb = (bits >> e) & 1u;
                float ex = nb ? __expf(lrelu(si + sv[e]) - mi) : 0.f;
                dsum += ex;
                afrag[e] = f2bf(ex);
            }
            const __hip_bfloat16* base =
                WhT2 + (size_t)((j0base >> 5) + ts) * 4096 + lane * 8;
            #pragma unroll
            for (int half = 0; half < 2; ++half) {
                bf16x8 bc[4];
                #pragma unroll
                for (int f = 0; f < 4; ++f)
                    bc[f] = *(const bf16x8*)(base + (half * 4 + f) * 512);
                #pragma unroll
                for (int f = 0; f < 4; ++f)
                    acc[half * 4 + f] =
                        __builtin_amdgcn_mfma_f32_16x16x32_bf16(afrag, bc[f], acc[half * 4 + f], 0, 0, 0);
            }
        }
    }
    {
        float v = dsum;
        v += __shfl_xor(v, 16);
        v += __shfl_xor(v, 32);
        if (lane < 16) atomicAdd(&denom[row0 + w * 16 + lane], v);
    }
    #pragma unroll
    for (int f = 0; f < 8; ++f)
        #pragma unroll
        for (int i = 0; i < 4; ++i) {
            int rr = row0 + w * 16 + kq * 4 + i;
            int cc = f * 16 + r16;
            atomicAdd(&y[(size_t)rr * H_DIM + cc], acc[f][i]);
        }
}

__global__ __launch_bounds__(256) void k_B_fb(const float* __restrict__ adj,
                                              const float* __restrict__ s,
                                              const float* __restrict__ denom,
                                              const unsigned int* __restrict__ smaxp,
                                              float* __restrict__ alpha) {
    const int NSTEP = N_NODES / 256;
    const int w = threadIdx.x >> 6, lane = threadIdx.x & 63;
    const int row = blockIdx.x * 4 + w;
    const float smax = mono2f(*smaxp);
    const float si = s[row];
    const float mi = lrelu(si + smax);
    const float d = denom[row];
    const float rd = d > 0.f ? 1.f / d : 0.f;
    float* arow = alpha + (size_t)row * N_NODES;
    const float* adjrow = adj + (size_t)row * N_NODES;
    #pragma unroll 4
    for (int t = 0; t < NSTEP; ++t) {
        int col = t * 256 + lane * 4;
        f32x4 a4 = __builtin_nontemporal_load((const f32x4*)&adjrow[col]);
        f32x4 sj = *(const f32x4*)&s[col];
        f32x4 o;
        o[0] = (a4[0] != 0.f) ? __expf(lrelu(si + sj[0]) - mi) * rd : 0.f;
        o[1] = (a4[1] != 0.f) ? __expf(lrelu(si + sj[1]) - mi) * rd : 0.f;
        o[2] = (a4[2] != 0.f) ? __expf(lrelu(si + sj[2]) - mi) * rd : 0.f;
        o[3] = (a4[3] != 0.f) ? __expf(lrelu(si + sj[3]) - mi) * rd : 0.f;
        __builtin_nontemporal_store(o, (f32x4*)&arow[col]);
    }
}

__global__ __launch_bounds__(256) void k_z_fb(const float* __restrict__ y,
                                              const float* __restrict__ denom,
                                              float* __restrict__ z) {
    int i = blockIdx.x * 256 + threadIdx.x;
    int row = i >> 7;
    float d = denom[row];
    float rd = d > 0.f ? 1.f / d : 0.f;
    float v = y[i] * rd;
    z[i] = 1.f / (1.f + __expf(-v));
}

extern "C" void kernel_launch(void* const* d_in, const int* in_sizes, int n_in,
                              void* d_out, int out_size, void* d_ws, size_t ws_size,
                              hipStream_t stream) {
    const float* h   = (const float*)d_in[0];
    const float* adj = (const float*)d_in[1];
    const float* Ww  = (const float*)d_in[2];
    const float* Wb  = (const float*)d_in[3];
    const float* a   = (const float*)d_in[4];

    float* z     = (float*)d_out;
    float* alpha = z + (size_t)N_NODES * H_DIM;

    char* ws = (char*)d_ws;
    float* y     = (float*)ws;  ws += sizeof(float) * (size_t)N_NODES * H_DIM;   // 4MB (fallback only)
    float* denom = (float*)ws;  ws += sizeof(float) * N_NODES;                   // 32KB
    unsigned int* smax = (unsigned int*)ws;  ws += 256;
    size_t zero_bytes = (size_t)(ws - (char*)d_ws);
    float* wa    = (float*)ws;  ws += sizeof(float) * IN_DIM;                    // 2KB
    float* ba    = (float*)ws;  ws += 256;
    __hip_bfloat16* WhT2 = (__hip_bfloat16*)ws;
    ws += sizeof(__hip_bfloat16) * (size_t)N_NODES * H_DIM;                      // 2MB
    float* s     = (float*)ws;  ws += sizeof(float) * N_NODES;                   // 32KB
    unsigned long long* bmask = (unsigned long long*)ws;
    ws += (size_t)N_NODES * NTW * sizeof(unsigned long long);                    // 8MB
    float* ypart = (float*)ws;
    ws += (size_t)NKB * N_NODES * H_DIM * sizeof(float);                         // 32MB
    size_t full_need = (size_t)(ws - (char*)d_ws);
    int use_full = (ws_size >= full_need) ? 1 : 0;

    hipLaunchKernelGGL(k_wa, dim3(1), dim3(256), 0, stream, Ww, Wb, a, wa, ba, smax);
    hipLaunchKernelGGL(k_s0, dim3(N_NODES / 4), dim3(256), 0, stream, h, wa, ba, s, smax);

    if (use_full) {
        hipLaunchKernelGGL(k_rowfront, dim3(NB_WH + NB_ROW), dim3(256), 0, stream,
                           h, Ww, Wb, WhT2, adj, bmask, s, smax, denom, alpha);
        hipLaunchKernelGGL(k_A, dim3(NB_A2), dim3(256), 0, stream,
                           bmask, WhT2, s, smax, ypart);
        hipLaunchKernelGGL(k_z2, dim3((N_NODES * H_DIM) / 256), dim3(256), 0, stream,
                           ypart, denom, z);
    } else {
        int n16 = (int)(zero_bytes / 16);
        hipLaunchKernelGGL(k_zero, dim3((n16 + 255) / 256), dim3(256), 0, stream,
                           (f32x4*)d_ws, n16);
        hipLaunchKernelGGL(k_wh_fb, dim3(NB_WH), dim3(256), 0, stream, h, Ww, Wb, WhT2);
        hipLaunchKernelGGL(k_A_fb, dim3(N_NODES / 64, NKB), dim3(256), 0, stream,
                           adj, WhT2, s, smax, denom, y);
        hipLaunchKernelGGL(k_B_fb, dim3(N_NODES / 4), dim3(256), 0, stream,
                           adj, s, denom, smax, alpha);
        hipLaunchKernelGGL(k_z_fb, dim3((N_NODES * H_DIM) / 256), dim3(256), 0, stream,
                           y, denom, z);
    }
}

// Round 21
// 222.847 us; speedup vs baseline: 1.1950x; 1.1950x over previous
//
#include <hip/hip_runtime.h>
#include <hip/hip_bf16.h>
#include <math.h>

#define N_NODES 8192
#define IN_DIM  512
#define H_DIM   128
#define KC      1024              // K-chunk per k_A block
#define NKB     (N_NODES / KC)    // 8
#define NTW     (N_NODES / 64)    // bitmask u64 words per row (128)
#define NB_WH   (N_NODES / 32)    // 256 wh tiles
#define NB_ROW  (N_NODES / 4)     // 2048 row-stream blocks (4 rows/block)
#define NB_A2   ((N_NODES / 128) * NKB)    // 512 k_A blocks (dual-frag, 32 rows/wave)

typedef __attribute__((ext_vector_type(8))) short bf16x8;
typedef __attribute__((ext_vector_type(4))) float f32x4;

__device__ __forceinline__ float lrelu(float x) { return fmaxf(x, 0.2f * x); }

__device__ __forceinline__ unsigned int f2mono(float x) {
    unsigned int b = __float_as_uint(x);
    return (b & 0x80000000u) ? ~b : (b | 0x80000000u);
}
__device__ __forceinline__ float mono2f(unsigned int u) {
    unsigned int b = (u & 0x80000000u) ? (u ^ 0x80000000u) : ~u;
    return __uint_as_float(b);
}

__device__ __forceinline__ short f2bf(float x) {
    union { __hip_bfloat16 h; short s; } cv;
    cv.h = __float2bfloat16(x);
    return cv.s;
}

// w_a = W_w^T @ a (512), b_a = W_b . a, smax init. One block.
__global__ __launch_bounds__(256) void k_wa(const float* __restrict__ Ww,
                                            const float* __restrict__ Wb,
                                            const float* __restrict__ a,
                                            float* __restrict__ wa,
                                            float* __restrict__ ba,
                                            unsigned int* __restrict__ smax) {
    const int t = threadIdx.x;
    #pragma unroll
    for (int kk = 0; kk < 2; ++kk) {
        int k = t + kk * 256;
        float sum = 0.f;
        #pragma unroll 8
        for (int c = 0; c < H_DIM; ++c)
            sum += Ww[(size_t)c * IN_DIM + k] * a[c];
        wa[k] = sum;
    }
    __shared__ float red[256];
    red[t] = (t < H_DIM) ? Wb[t] * a[t] : 0.f;
    __syncthreads();
    for (int off = 128; off > 0; off >>= 1) {
        if (t < off) red[t] += red[t + off];
        __syncthreads();
    }
    if (t == 0) { ba[0] = red[0]; *smax = 0u; }
}

// s_i = h_i . w_a + b_a ; smax via mapped atomicMax. 4 rows/block (wave each).
__global__ __launch_bounds__(256) void k_s0(const float* __restrict__ h,
                                            const float* __restrict__ wa,
                                            const float* __restrict__ ba,
                                            float* __restrict__ s,
                                            unsigned int* __restrict__ smax) {
    const int w = threadIdx.x >> 6, lane = threadIdx.x & 63;
    const int row = blockIdx.x * 4 + w;
    const float* hp = h + (size_t)row * IN_DIM + lane * 8;
    f32x4 h0 = *(const f32x4*)(hp);
    f32x4 h1 = *(const f32x4*)(hp + 4);
    f32x4 w0 = *(const f32x4*)(wa + lane * 8);
    f32x4 w1 = *(const f32x4*)(wa + lane * 8 + 4);
    float v = h0[0]*w0[0] + h0[1]*w0[1] + h0[2]*w0[2] + h0[3]*w0[3]
            + h1[0]*w1[0] + h1[1]*w1[1] + h1[2]*w1[2] + h1[3]*w1[3];
    #pragma unroll
    for (int off = 32; off > 0; off >>= 1) v += __shfl_down(v, off);
    __shared__ float bmax[4];
    if (lane == 0) { float sv = v + ba[0]; s[row] = sv; bmax[w] = sv; }
    __syncthreads();
    if (threadIdx.x == 0) {
        float m = fmaxf(fmaxf(bmax[0], bmax[1]), fmaxf(bmax[2], bmax[3]));
        atomicMax(smax, f2mono(m));
    }
}

// ---------------- fused rowfront: k_wh || (mask + denom + alpha) -------------
// r20 post-mortem: wh's 43KB static LDS was allocated for EVERY block
// (including the 2048 stream blocks) -> 3 blocks/CU -> the 536MB stream ran
// latency-bound at 2.55 TB/s (Occupancy 29%). Fix: BK=32 wh tiles -> LDS
// 21504B -> ~6 blocks/CU (VGPR=80 binds), doubling resident waves for the
// stream. wh pays 16 outer iters instead of 8 (noise on a ~25us sub-phase).
__global__ __launch_bounds__(256) void k_rowfront(const float* __restrict__ h,
                                                  const float* __restrict__ Ww,
                                                  const float* __restrict__ Wb,
                                                  __hip_bfloat16* __restrict__ WhT2,
                                                  const float* __restrict__ adj,
                                                  unsigned long long* __restrict__ bm,
                                                  const float* __restrict__ s,
                                                  const unsigned int* __restrict__ smaxp,
                                                  float* __restrict__ denom,
                                                  float* __restrict__ alpha) {
    __shared__ float hT[32][32 + 4];       // 4.5KB
    __shared__ float wT[32][H_DIM + 4];    // 16.9KB  (total 21504B)
    const int tid = threadIdx.x;
    const int bx = blockIdx.x;

    if (bx < NB_WH) {
        // ---- Wh GEMM (BK=32) -> WhT2 fragment-swizzled bf16 ----
        const int klane = tid & 31;        // k within tile
        const int rbase = tid >> 5;        // 0..7
        const int trm = tid >> 5, tcm = tid & 31;
        const int row0 = bx * 32;

        float acc[4][4] = {};
        for (int k0 = 0; k0 < IN_DIM; k0 += 32) {
            __syncthreads();
            #pragma unroll
            for (int p = 0; p < 4; ++p) {
                int r = rbase + 8 * p;
                hT[klane][r] = h[(size_t)(row0 + r) * IN_DIM + k0 + klane];
            }
            #pragma unroll
            for (int p = 0; p < 16; ++p) {
                int c = rbase + 8 * p;
                wT[klane][c] = Ww[(size_t)c * IN_DIM + k0 + klane];
            }
            __syncthreads();
            #pragma unroll 8
            for (int kk = 0; kk < 32; ++kk) {
                f32x4 a4 = *(const f32x4*)&hT[kk][4 * trm];
                f32x4 b4 = *(const f32x4*)&wT[kk][4 * tcm];
                #pragma unroll
                for (int i = 0; i < 4; ++i)
                    #pragma unroll
                    for (int j = 0; j < 4; ++j)
                        acc[i][j] = fmaf(a4[i], b4[j], acc[i][j]);
            }
        }
        f32x4 wb4 = *(const f32x4*)&Wb[4 * tcm];
        #pragma unroll
        for (int i = 0; i < 4; ++i) {
            int row = row0 + 4 * trm + i;          // node j
            int ts = row >> 5, kq = (row >> 3) & 3, e = row & 7;
            #pragma unroll
            for (int jj = 0; jj < 4; ++jj) {
                int c = 4 * tcm + jj;
                int f = c >> 4, r16 = c & 15;
                WhT2[((size_t)(ts * 8 + f) * 64 + kq * 16 + r16) * 8 + e] =
                    __float2bfloat16(acc[i][jj] + wb4[jj]);
            }
        }
    } else {
        const int lane = tid & 63;
        const int row = (bx - NB_WH) * 4 + (tid >> 6);
        const float* arow = adj + (size_t)row * N_NODES;
        unsigned long long* mrow = bm + (size_t)row * NTW;
        const float smax = mono2f(*smaxp);
        const float si = s[row];
        const float mi = lrelu(si + smax);
        float dsum = 0.f;
        unsigned int mybits[4] = {0u, 0u, 0u, 0u};   // this lane's 128 mask bits

        // ---- sweep 1: adj stream -> bits (regs + global bitmask), denom ----
        #pragma unroll 4
        for (int c = 0; c < N_NODES / 256; ++c) {    // 32 iters, 1KB/wave each
            int col = c * 256 + lane * 4;
            f32x4 a4 = __builtin_nontemporal_load((const f32x4*)(arow + col));
            f32x4 sj = *(const f32x4*)&s[col];
            unsigned int b4 = 0u;
            #pragma unroll
            for (int q = 0; q < 4; ++q) {
                bool nb = (a4[q] != 0.f);
                b4 |= nb ? (1u << q) : 0u;
                dsum += nb ? __expf(lrelu(si + sj[q]) - mi) : 0.f;
            }
            mybits[c >> 3] |= b4 << ((c & 7) * 4);
            // global bitmask word for k_A (cross-lane pack within 16-lane group)
            unsigned long long v = (unsigned long long)b4 << (4 * (lane & 15));
            v |= __shfl_xor(v, 1);
            v |= __shfl_xor(v, 2);
            v |= __shfl_xor(v, 4);
            v |= __shfl_xor(v, 8);
            if ((lane & 15) == 0)
                mrow[c * 4 + (lane >> 4)] = v;
        }
        // full 64-lane butterfly: every lane gets the row total
        #pragma unroll
        for (int off = 1; off < 64; off <<= 1) dsum += __shfl_xor(dsum, off);
        if (lane == 0) denom[row] = dsum;
        const float rd = dsum > 0.f ? 1.f / dsum : 0.f;

        // ---- sweep 2: alpha row from register bits (s is L1-resident) ----
        float* arw = alpha + (size_t)row * N_NODES;
        #pragma unroll 4
        for (int c = 0; c < N_NODES / 256; ++c) {
            int col = c * 256 + lane * 4;
            unsigned int b4 = (mybits[c >> 3] >> ((c & 7) * 4)) & 0xfu;
            f32x4 sj = *(const f32x4*)&s[col];
            f32x4 o;
            o[0] = (b4 & 1u) ? __expf(lrelu(si + sj[0]) - mi) * rd : 0.f;
            o[1] = (b4 & 2u) ? __expf(lrelu(si + sj[1]) - mi) * rd : 0.f;
            o[2] = (b4 & 4u) ? __expf(lrelu(si + sj[2]) - mi) * rd : 0.f;
            o[3] = (b4 & 8u) ? __expf(lrelu(si + sj[3]) - mi) * rd : 0.f;
            __builtin_nontemporal_store(o, (f32x4*)&arw[col]);
        }
    }
}

// ---------------- k_A standalone: dual-frag MFMA -------------------------
__global__ __launch_bounds__(256) void k_A(const unsigned long long* __restrict__ bm,
                                           const __hip_bfloat16* __restrict__ WhT2,
                                           const float* __restrict__ s,
                                           const unsigned int* __restrict__ smaxp,
                                           float* __restrict__ ypart) {
    const int lane = threadIdx.x & 63;
    const int w    = threadIdx.x >> 6;
    const int r16  = lane & 15;
    const int kq   = lane >> 4;
    const int xb   = blockIdx.x & 63;
    const int yb   = blockIdx.x >> 6;
    const int rowB = xb * 128 + w * 32;
    const int j0   = yb * KC;
    const int rowA0 = rowB + r16;
    const int rowA1 = rowB + 16 + r16;

    const float smax = mono2f(*smaxp);
    const float si0 = s[rowA0], si1 = s[rowA1];
    const float mi0 = lrelu(si0 + smax), mi1 = lrelu(si1 + smax);

    f32x4 acc0[8], acc1[8];
    {
        f32x4 zv = {0.f, 0.f, 0.f, 0.f};
        #pragma unroll
        for (int f = 0; f < 8; ++f) { acc0[f] = zv; acc1[f] = zv; }
    }
    const float* sp = s + j0 + kq * 8;
    const unsigned long long* mrow0 = bm + (size_t)rowA0 * NTW + (j0 >> 6);
    const unsigned long long* mrow1 = bm + (size_t)rowA1 * NTW + (j0 >> 6);

    for (int bs = 0; bs < KC / 64; ++bs) {
        unsigned long long m64a = mrow0[bs];
        unsigned long long m64b = mrow1[bs];
        #pragma unroll
        for (int sub = 0; sub < 2; ++sub) {
            const int ts = bs * 2 + sub;
            unsigned int bits0 = (unsigned int)(m64a >> (sub * 32 + kq * 8)) & 0xffu;
            unsigned int bits1 = (unsigned int)(m64b >> (sub * 32 + kq * 8)) & 0xffu;

            f32x4 sc0 = *(const f32x4*)(sp + ts * 32);
            f32x4 sc1 = *(const f32x4*)(sp + ts * 32 + 4);
            float sv[8] = {sc0[0], sc0[1], sc0[2], sc0[3], sc1[0], sc1[1], sc1[2], sc1[3]};
            bf16x8 af0, af1;
            #pragma unroll
            for (int e = 0; e < 8; ++e) {
                float ex0 = ((bits0 >> e) & 1u) ? __expf(lrelu(si0 + sv[e]) - mi0) : 0.f;
                float ex1 = ((bits1 >> e) & 1u) ? __expf(lrelu(si1 + sv[e]) - mi1) : 0.f;
                af0[e] = f2bf(ex0);
                af1[e] = f2bf(ex1);
            }
            const __hip_bfloat16* base =
                WhT2 + (size_t)((j0 >> 5) + ts) * 4096 + lane * 8;
            #pragma unroll
            for (int half = 0; half < 2; ++half) {
                bf16x8 bc[4];
                #pragma unroll
                for (int f = 0; f < 4; ++f)
                    bc[f] = *(const bf16x8*)(base + (half * 4 + f) * 512);
                #pragma unroll
                for (int f = 0; f < 4; ++f) {
                    acc0[half * 4 + f] =
                        __builtin_amdgcn_mfma_f32_16x16x32_bf16(af0, bc[f], acc0[half * 4 + f], 0, 0, 0);
                    acc1[half * 4 + f] =
                        __builtin_amdgcn_mfma_f32_16x16x32_bf16(af1, bc[f], acc1[half * 4 + f], 0, 0, 0);
                }
            }
        }
    }
    float* yp = ypart + (size_t)yb * N_NODES * H_DIM;
    #pragma unroll
    for (int f = 0; f < 8; ++f)
        #pragma unroll
        for (int i = 0; i < 4; ++i) {
            int cc = f * 16 + r16;
            yp[(size_t)(rowB + kq * 4 + i) * H_DIM + cc] = acc0[f][i];
            yp[(size_t)(rowB + 16 + kq * 4 + i) * H_DIM + cc] = acc1[f][i];
        }
}

// z = sigmoid(sum_p ypart[p]/denom)
__global__ __launch_bounds__(256) void k_z2(const float* __restrict__ ypart,
                                            const float* __restrict__ denom,
                                            float* __restrict__ z) {
    int i = blockIdx.x * 256 + threadIdx.x;
    int row = i >> 7;
    float d = denom[row];
    float rd = d > 0.f ? 1.f / d : 0.f;
    float v = 0.f;
    #pragma unroll
    for (int p = 0; p < NKB; ++p)
        v += ypart[(size_t)p * N_NODES * H_DIM + i];
    v *= rd;
    z[i] = 1.f / (1.f + __expf(-v));
}

// ---------------- fallback path (ws too small): serial, adj-direct ----------------
__global__ __launch_bounds__(256) void k_zero(f32x4* __restrict__ p, int n16) {
    int i = blockIdx.x * 256 + threadIdx.x;
    if (i < n16) {
        f32x4 zv = {0.f, 0.f, 0.f, 0.f};
        __builtin_nontemporal_store(zv, p + i);
    }
}

__global__ __launch_bounds__(256) void k_wh_fb(const float* __restrict__ h,
                                               const float* __restrict__ Ww,
                                               const float* __restrict__ Wb,
                                               __hip_bfloat16* __restrict__ WhT2) {
    __shared__ float hT[32][32 + 4];
    __shared__ float wT[32][H_DIM + 4];
    const int tid = threadIdx.x;
    const int klane = tid & 31;
    const int rbase = tid >> 5;
    const int trm = tid >> 5, tcm = tid & 31;
    const int row0 = blockIdx.x * 32;

    float acc[4][4] = {};
    for (int k0 = 0; k0 < IN_DIM; k0 += 32) {
        __syncthreads();
        #pragma unroll
        for (int p = 0; p < 4; ++p) {
            int r = rbase + 8 * p;
            hT[klane][r] = h[(size_t)(row0 + r) * IN_DIM + k0 + klane];
        }
        #pragma unroll
        for (int p = 0; p < 16; ++p) {
            int c = rbase + 8 * p;
            wT[klane][c] = Ww[(size_t)c * IN_DIM + k0 + klane];
        }
        __syncthreads();
        #pragma unroll 8
        for (int kk = 0; kk < 32; ++kk) {
            f32x4 a4 = *(const f32x4*)&hT[kk][4 * trm];
            f32x4 b4 = *(const f32x4*)&wT[kk][4 * tcm];
            #pragma unroll
            for (int i = 0; i < 4; ++i)
                #pragma unroll
                for (int j = 0; j < 4; ++j)
                    acc[i][j] = fmaf(a4[i], b4[j], acc[i][j]);
        }
    }
    f32x4 wb4 = *(const f32x4*)&Wb[4 * tcm];
    #pragma unroll
    for (int i = 0; i < 4; ++i) {
        int row = row0 + 4 * trm + i;
        int ts = row >> 5, kq = (row >> 3) & 3, e = row & 7;
        #pragma unroll
        for (int jj = 0; jj < 4; ++jj) {
            int c = 4 * tcm + jj;
            int f = c >> 4, r16 = c & 15;
            WhT2[((size_t)(ts * 8 + f) * 64 + kq * 16 + r16) * 8 + e] =
                __float2bfloat16(acc[i][jj] + wb4[jj]);
        }
    }
}

__global__ __launch_bounds__(256) void k_A_fb(const float* __restrict__ adj,
                                              const __hip_bfloat16* __restrict__ WhT2,
                                              const float* __restrict__ s,
                                              const unsigned int* __restrict__ smaxp,
                                              float* __restrict__ denom,
                                              float* __restrict__ y) {
    __shared__ unsigned char msk[64 * 64];
    const int tid  = threadIdx.x;
    const int lane = tid & 63;
    const int w    = tid >> 6;
    const int r16  = lane & 15;
    const int kq   = lane >> 4;
    const int row0 = blockIdx.x * 64;
    const int j0base = blockIdx.y * KC;
    const int rowA = row0 + w * 16 + r16;

    const float smax = mono2f(*smaxp);
    const float si = s[rowA];
    const float mi = lrelu(si + smax);

    f32x4 acc[8];
    {
        f32x4 zv = {0.f, 0.f, 0.f, 0.f};
        #pragma unroll
        for (int f = 0; f < 8; ++f) acc[f] = zv;
    }
    float dsum = 0.f;
    const float* sp = s + j0base + kq * 8;

    int sRow[4], sCol[4];
    #pragma unroll
    for (int p = 0; p < 4; ++p) {
        int seg = p * 256 + tid;
        sRow[p] = seg >> 4;
        sCol[p] = (seg & 15) * 4;
    }
    const int NBIG = KC / 64;
    f32x4 areg[4];
    #pragma unroll
    for (int p = 0; p < 4; ++p)
        areg[p] = __builtin_nontemporal_load(
            (const f32x4*)(adj + (size_t)(row0 + sRow[p]) * N_NODES + j0base + sCol[p]));

    for (int bs = 0; bs < NBIG; ++bs) {
        __syncthreads();
        #pragma unroll
        for (int p = 0; p < 4; ++p) {
            f32x4 a4 = areg[p];
            unsigned int mwd = 0u;
            mwd |= (a4[0] != 0.f) ? 0x00000001u : 0u;
            mwd |= (a4[1] != 0.f) ? 0x00000100u : 0u;
            mwd |= (a4[2] != 0.f) ? 0x00010000u : 0u;
            mwd |= (a4[3] != 0.f) ? 0x01000000u : 0u;
            int r = sRow[p], c = sCol[p];
            int slot = (c >> 3) ^ (r & 7);
            *(unsigned int*)&msk[r * 64 + (slot << 3) + (c & 7)] = mwd;
        }
        __syncthreads();
        if (bs + 1 < NBIG) {
            const int j1 = j0base + (bs + 1) * 64;
            #pragma unroll
            for (int p = 0; p < 4; ++p)
                areg[p] = __builtin_nontemporal_load(
                    (const f32x4*)(adj + (size_t)(row0 + sRow[p]) * N_NODES + j1 + sCol[p]));
        }
        #pragma unroll
        for (int sub = 0; sub < 2; ++sub) {
            const int ts = bs * 2 + sub;
            const int rT = w * 16 + r16;
            const int slotR = (sub * 4 + kq) ^ (r16 & 7);
            unsigned long long m8 = *(const unsigned long long*)&msk[rT * 64 + (slotR << 3)];
            unsigned int bits = (unsigned int)((m8 * 0x0102040810204080ull) >> 56) & 0xffu;

            f32x4 sc0 = *(const f32x4*)(sp + ts * 32);
            f32x4 sc1 = *(const f32x4*)(sp + ts * 32 + 4);
            float sv[8] = {sc0[0], sc0[1], sc0[2], sc0[3], sc1[0], sc1[1], sc1[2], sc1[3]};
            bf16x8 afrag;
            #pragma unroll
            for (int e = 0; e < 8; ++e) {
                bool nb = (bits >> e) & 1u;
                float ex = nb ? __expf(lrelu(si + sv[e]) - mi) : 0.f;
                dsum += ex;
                afrag[e] = f2bf(ex);
            }
            const __hip_bfloat16* base =
                WhT2 + (size_t)((j0base >> 5) + ts) * 4096 + lane * 8;
            #pragma unroll
            for (int half = 0; half < 2; ++half) {
                bf16x8 bc[4];
                #pragma unroll
                for (int f = 0; f < 4; ++f)
                    bc[f] = *(const bf16x8*)(base + (half * 4 + f) * 512);
                #pragma unroll
                for (int f = 0; f < 4; ++f)
                    acc[half * 4 + f] =
                        __builtin_amdgcn_mfma_f32_16x16x32_bf16(afrag, bc[f], acc[half * 4 + f], 0, 0, 0);
            }
        }
    }
    {
        float v = dsum;
        v += __shfl_xor(v, 16);
        v += __shfl_xor(v, 32);
        if (lane < 16) atomicAdd(&denom[row0 + w * 16 + lane], v);
    }
    #pragma unroll
    for (int f = 0; f < 8; ++f)
        #pragma unroll
        for (int i = 0; i < 4; ++i) {
            int rr = row0 + w * 16 + kq * 4 + i;
            int cc = f * 16 + r16;
            atomicAdd(&y[(size_t)rr * H_DIM + cc], acc[f][i]);
        }
}

__global__ __launch_bounds__(256) void k_B_fb(const float* __restrict__ adj,
                                              const float* __restrict__ s,
                                              const float* __restrict__ denom,
                                              const unsigned int* __restrict__ smaxp,
                                              float* __restrict__ alpha) {
    const int NSTEP = N_NODES / 256;
    const int w = threadIdx.x >> 6, lane = threadIdx.x & 63;
    const int row = blockIdx.x * 4 + w;
    const float smax = mono2f(*smaxp);
    const float si = s[row];
    const float mi = lrelu(si + smax);
    const float d = denom[row];
    const float rd = d > 0.f ? 1.f / d : 0.f;
    float* arow = alpha + (size_t)row * N_NODES;
    const float* adjrow = adj + (size_t)row * N_NODES;
    #pragma unroll 4
    for (int t = 0; t < NSTEP; ++t) {
        int col = t * 256 + lane * 4;
        f32x4 a4 = __builtin_nontemporal_load((const f32x4*)&adjrow[col]);
        f32x4 sj = *(const f32x4*)&s[col];
        f32x4 o;
        o[0] = (a4[0] != 0.f) ? __expf(lrelu(si + sj[0]) - mi) * rd : 0.f;
        o[1] = (a4[1] != 0.f) ? __expf(lrelu(si + sj[1]) - mi) * rd : 0.f;
        o[2] = (a4[2] != 0.f) ? __expf(lrelu(si + sj[2]) - mi) * rd : 0.f;
        o[3] = (a4[3] != 0.f) ? __expf(lrelu(si + sj[3]) - mi) * rd : 0.f;
        __builtin_nontemporal_store(o, (f32x4*)&arow[col]);
    }
}

__global__ __launch_bounds__(256) void k_z_fb(const float* __restrict__ y,
                                              const float* __restrict__ denom,
                                              float* __restrict__ z) {
    int i = blockIdx.x * 256 + threadIdx.x;
    int row = i >> 7;
    float d = denom[row];
    float rd = d > 0.f ? 1.f / d : 0.f;
    float v = y[i] * rd;
    z[i] = 1.f / (1.f + __expf(-v));
}

extern "C" void kernel_launch(void* const* d_in, const int* in_sizes, int n_in,
                              void* d_out, int out_size, void* d_ws, size_t ws_size,
                              hipStream_t stream) {
    const float* h   = (const float*)d_in[0];
    const float* adj = (const float*)d_in[1];
    const float* Ww  = (const float*)d_in[2];
    const float* Wb  = (const float*)d_in[3];
    const float* a   = (const float*)d_in[4];

    float* z     = (float*)d_out;
    float* alpha = z + (size_t)N_NODES * H_DIM;

    char* ws = (char*)d_ws;
    float* y     = (float*)ws;  ws += sizeof(float) * (size_t)N_NODES * H_DIM;   // 4MB (fallback only)
    float* denom = (float*)ws;  ws += sizeof(float) * N_NODES;                   // 32KB
    unsigned int* smax = (unsigned int*)ws;  ws += 256;
    size_t zero_bytes = (size_t)(ws - (char*)d_ws);
    float* wa    = (float*)ws;  ws += sizeof(float) * IN_DIM;                    // 2KB
    float* ba    = (float*)ws;  ws += 256;
    __hip_bfloat16* WhT2 = (__hip_bfloat16*)ws;
    ws += sizeof(__hip_bfloat16) * (size_t)N_NODES * H_DIM;                      // 2MB
    float* s     = (float*)ws;  ws += sizeof(float) * N_NODES;                   // 32KB
    unsigned long long* bmask = (unsigned long long*)ws;
    ws += (size_t)N_NODES * NTW * sizeof(unsigned long long);                    // 8MB
    float* ypart = (float*)ws;
    ws += (size_t)NKB * N_NODES * H_DIM * sizeof(float);                         // 32MB
    size_t full_need = (size_t)(ws - (char*)d_ws);
    int use_full = (ws_size >= full_need) ? 1 : 0;

    hipLaunchKernelGGL(k_wa, dim3(1), dim3(256), 0, stream, Ww, Wb, a, wa, ba, smax);
    hipLaunchKernelGGL(k_s0, dim3(N_NODES / 4), dim3(256), 0, stream, h, wa, ba, s, smax);

    if (use_full) {
        hipLaunchKernelGGL(k_rowfront, dim3(NB_WH + NB_ROW), dim3(256), 0, stream,
                           h, Ww, Wb, WhT2, adj, bmask, s, smax, denom, alpha);
        hipLaunchKernelGGL(k_A, dim3(NB_A2), dim3(256), 0, stream,
                           bmask, WhT2, s, smax, ypart);
        hipLaunchKernelGGL(k_z2, dim3((N_NODES * H_DIM) / 256), dim3(256), 0, stream,
                           ypart, denom, z);
    } else {
        int n16 = (int)(zero_bytes / 16);
        hipLaunchKernelGGL(k_zero, dim3((n16 + 255) / 256), dim3(256), 0, stream,
                           (f32x4*)d_ws, n16);
        hipLaunchKernelGGL(k_wh_fb, dim3(NB_WH), dim3(256), 0, stream, h, Ww, Wb, WhT2);
        hipLaunchKernelGGL(k_A_fb, dim3(N_NODES / 64, NKB), dim3(256), 0, stream,
                           adj, WhT2, s, smax, denom, y);
        hipLaunchKernelGGL(k_B_fb, dim3(N_NODES / 4), dim3(256), 0, stream,
                           adj, s, denom, smax, alpha);
        hipLaunchKernelGGL(k_z_fb, dim3((N_NODES * H_DIM) / 256), dim3(256), 0, stream,
                           y, denom, z);
    }
}